// Round 1
// baseline (212.418 us; speedup 1.0000x reference)
//
#include <hip/hip_runtime.h>

#define BB  4
#define LL  512
#define HID 256
#define PAi 32
#define OO  64

// -------- Kernel 1: h[b,l,p] = dot(hidden[b,l,:], W_in[p,:]) + b_in[p] --------
// grid = B*L/8 blocks, 256 threads. Each block: 8 rows, thread (r=tid>>5, p=tid&31).
__global__ __launch_bounds__(256) void k_in(const float* __restrict__ hidden,
                                            const float* __restrict__ W_in,
                                            const float* __restrict__ b_in,
                                            float* __restrict__ h) {
    __shared__ float4 hid[8 * 64];  // 8 rows x 256 floats = 8 KB
    const int tid  = threadIdx.x;
    const int row0 = blockIdx.x * 8;  // row in [0, B*L)
    const float4* src = (const float4*)(hidden + (size_t)row0 * HID);
    hid[tid]       = src[tid];
    hid[tid + 256] = src[tid + 256];
    __syncthreads();
    const int p = tid & 31;
    const int r = tid >> 5;
    const float4* w = (const float4*)(W_in + (size_t)p * HID);
    float acc = 0.f;
#pragma unroll
    for (int k = 0; k < 64; ++k) {
        float4 hv = hid[r * 64 + k];
        float4 wv = w[k];
        acc += hv.x * wv.x + hv.y * wv.y + hv.z * wv.z + hv.w * wv.w;
    }
    h[(size_t)(row0 + r) * PAi + p] = acc + b_in[p];
}

// -------- Kernel 2: t[b,j,o,q] = sum_p h[b,j,p] * W_out[o, p*32+q] --------
// grid = B*L/8 blocks, 256 threads. Thread: qg=tid&7 (q=4*qg..), o1=tid>>3 (o in {o1,o1+32}),
// 8 j-rows per block so W_out is read once per block and reused 8x from registers.
__global__ __launch_bounds__(256) void k_mid(const float* __restrict__ h,
                                             const float* __restrict__ W_out,
                                             float* __restrict__ t) {
    __shared__ __attribute__((aligned(16))) float hst[PAi * 8];  // [p][r] transposed
    const int tid  = threadIdx.x;
    const int row0 = blockIdx.x * 8;
    {
        const int p = tid & 31, r = tid >> 5;
        hst[p * 8 + r] = h[(size_t)(row0 + r) * PAi + p];
    }
    __syncthreads();
    const int qg = tid & 7;
    const int o1 = tid >> 3;  // 0..31
    const float4* W4 = (const float4*)W_out;  // [O][PA][8] float4
    float4 accA[8], accB[8];
#pragma unroll
    for (int r = 0; r < 8; ++r) {
        accA[r] = float4{0, 0, 0, 0};
        accB[r] = float4{0, 0, 0, 0};
    }
#pragma unroll 4
    for (int p = 0; p < PAi; ++p) {
        float4 wa = W4[(o1 * PAi + p) * 8 + qg];
        float4 wb = W4[((o1 + 32) * PAi + p) * 8 + qg];
        float4 h1 = *(const float4*)&hst[p * 8];
        float4 h2 = *(const float4*)&hst[p * 8 + 4];
        float hr[8] = {h1.x, h1.y, h1.z, h1.w, h2.x, h2.y, h2.z, h2.w};
#pragma unroll
        for (int r = 0; r < 8; ++r) {
            accA[r].x += hr[r] * wa.x; accA[r].y += hr[r] * wa.y;
            accA[r].z += hr[r] * wa.z; accA[r].w += hr[r] * wa.w;
            accB[r].x += hr[r] * wb.x; accB[r].y += hr[r] * wb.y;
            accB[r].z += hr[r] * wb.z; accB[r].w += hr[r] * wb.w;
        }
    }
#pragma unroll
    for (int r = 0; r < 8; ++r) {
        float4* dst = (float4*)(t + (size_t)(row0 + r) * OO * PAi);
        dst[o1 * 8 + qg]        = accA[r];
        dst[(o1 + 32) * 8 + qg] = accB[r];
    }
}

// -------- Kernel 3: out[b,i,j,o] = dot(t[b,j,o,:], h[b,i,:]) + b_out[o] + pw[b,i,j,o] --------
// grid = (L/TJ, L/TI, B), 256 threads: o=tid&63, jj=tid>>6. Each thread holds its
// 32-float t fragment in VGPRs, loops TI i-rows; h rows broadcast from LDS.
#define TI 32
#define TJ 4
__global__ __launch_bounds__(256) void k_out(const float* __restrict__ t,
                                             const float* __restrict__ h,
                                             const float* __restrict__ pw,
                                             const float* __restrict__ b_out,
                                             float* __restrict__ out) {
    __shared__ float4 hs4[TI * 8];  // 32 rows x 32 floats = 4 KB
    const int tid = threadIdx.x;
    const int b   = blockIdx.z;
    const int i0  = blockIdx.y * TI;
    const int j0  = blockIdx.x * TJ;
    const int o   = tid & 63;
    const int jj  = tid >> 6;
    const int j   = j0 + jj;
    // stage h[b, i0:i0+32, 0:32] (256 float4, one per thread, coalesced)
    hs4[tid] = ((const float4*)(h + ((size_t)b * LL + i0) * PAi))[tid];
    // per-thread t fragment
    float tq[PAi];
    {
        const float4* tp = (const float4*)(t + (((size_t)b * LL + j) * OO + o) * PAi);
#pragma unroll
        for (int k = 0; k < 8; ++k) {
            float4 v = tp[k];
            tq[4 * k] = v.x; tq[4 * k + 1] = v.y; tq[4 * k + 2] = v.z; tq[4 * k + 3] = v.w;
        }
    }
    const float bo = b_out[o];
    __syncthreads();
    const size_t base = (((size_t)b * LL + i0) * LL + j) * OO + o;
#pragma unroll 4
    for (int ii = 0; ii < TI; ++ii) {
        float acc = 0.f;
#pragma unroll
        for (int k = 0; k < 8; ++k) {
            float4 hv = hs4[ii * 8 + k];
            acc += tq[4 * k] * hv.x + tq[4 * k + 1] * hv.y +
                   tq[4 * k + 2] * hv.z + tq[4 * k + 3] * hv.w;
        }
        const size_t idx = base + (size_t)ii * (LL * OO);
        out[idx] = acc + bo + pw[idx];
    }
}

extern "C" void kernel_launch(void* const* d_in, const int* in_sizes, int n_in,
                              void* d_out, int out_size, void* d_ws, size_t ws_size,
                              hipStream_t stream) {
    const float* hidden = (const float*)d_in[0];
    const float* pw     = (const float*)d_in[1];
    const float* W_in   = (const float*)d_in[2];
    const float* b_in   = (const float*)d_in[3];
    const float* W_out  = (const float*)d_in[4];
    const float* b_out  = (const float*)d_in[5];
    float* out = (float*)d_out;

    float* h = (float*)d_ws;                       // B*L*PA      = 65536 floats (256 KB)
    float* t = h + (size_t)BB * LL * PAi;          // B*L*O*PA    = 4194304 floats (16 MB)

    k_in <<<dim3(BB * LL / 8), 256, 0, stream>>>(hidden, W_in, b_in, h);
    k_mid<<<dim3(BB * LL / 8), 256, 0, stream>>>(h, W_out, t);
    k_out<<<dim3(LL / TJ, LL / TI, BB), 256, 0, stream>>>(t, h, pw, b_out, out);
}